// Round 2
// baseline (465.713 us; speedup 1.0000x reference)
//
#include <hip/hip_runtime.h>
#include <hip/hip_fp16.h>
#include <math.h>

#define IN_F 64
#define OUT_F 32
#define NEG_SLOPE 0.2f

#define BK_SHIFT 7
#define BK 128           // nodes per bucket
#define NBMAX 1024       // max buckets (N <= 131072)
#define NBLKA 256        // edge-pass block count (= per-bucket scan width)

typedef _Float16 half8_t __attribute__((ext_vector_type(8)));
typedef float float4_t __attribute__((ext_vector_type(4)));
typedef int int4_t __attribute__((ext_vector_type(4)));

__device__ __forceinline__ float leaky(float v) {
    return (v > 0.0f) ? v : NEG_SLOPE * v;
}

__device__ __forceinline__ float2 h2f(int w) {
    __half2 h = *reinterpret_cast<__half2*>(&w);
    return __half22float2(h);
}

// Inclusive block scan, 256 threads. wsum: >=4-int LDS scratch.
__device__ __forceinline__ int incScan256(int v, int tid, int* wsum) {
    const int lane = tid & 63, wid = tid >> 6;
    #pragma unroll
    for (int m = 1; m < 64; m <<= 1) {
        int u = __shfl_up(v, m);
        if (lane >= m) v += u;
    }
    if (lane == 63) wsum[wid] = v;
    __syncthreads();
    int add = 0;
    for (int k = 0; k < wid; ++k) add += wsum[k];
    __syncthreads();
    return v + add;
}

// Inclusive block scan, 512 threads. wsum: >=8-int LDS scratch.
__device__ __forceinline__ int incScan512(int v, int tid, int* wsum) {
    const int lane = tid & 63, wid = tid >> 6;
    #pragma unroll
    for (int m = 1; m < 64; m <<= 1) {
        int u = __shfl_up(v, m);
        if (lane >= m) v += u;
    }
    if (lane == 63) wsum[wid] = v;
    __syncthreads();
    int add = 0;
    for (int k = 0; k < wid; ++k) add += wsum[k];
    __syncthreads();
    return v + add;
}

// Fused: blocks [0, PB) MFMA projection (16 nodes/wave, 64/block, no LDS);
// blocks [PB, PB+NBLKA) coarse histogram (LDS).
// MFMA layouts (HW-verified, cdna_hip_programming.md §3 / m89/m120):
//   A[m=lane&15][k=(lane>>4)*8+j]   B[n=lane&15][k=(lane>>4)*8+j]
//   C/D: col(n)=lane&15, row(m)=(lane>>4)*4+reg
__global__ __launch_bounds__(256) void k_projhist(
        const float* __restrict__ x, const float* __restrict__ W,
        const float* __restrict__ att_src, const float* __restrict__ att_dst,
        __half2* __restrict__ h2, float* __restrict__ asrc, float* __restrict__ adst,
        const int* __restrict__ dst, int* __restrict__ hist,
        int N, int NB, int E, int epb, int PB) {
    __shared__ int smem[2560];               // 10 KB (hist role only)
    const int tid = threadIdx.x;

    if (blockIdx.x >= PB) {
        // ---- coarse histogram role: hist[b*NBLKA + blk] ----
        int* lh = smem;
        const int blk = blockIdx.x - PB;
        for (int i = tid; i < NB; i += 256) lh[i] = 0;
        __syncthreads();
        const int e0 = blk * epb, e1 = min(E, e0 + epb);
        for (int e = e0 + tid; e < e1; e += 256) atomicAdd(&lh[dst[e] >> BK_SHIFT], 1);
        __syncthreads();
        for (int b = tid; b < NB; b += 256) hist[(size_t)b * NBLKA + blk] = lh[b];
        return;
    }

    // ---- MFMA projection role ----
    const int wv   = tid >> 6;               // wave 0..3
    const int lane = tid & 63;
    const int m    = lane & 15;              // node-in-16 (A) / channel-in-group (B, C/D)
    const int quad = lane >> 4;              // 0..3
    const int node0 = (blockIdx.x * 4 + wv) * 16;
    if (node0 >= N) return;

    const int kb = quad * 8;
    // B fragments (W is 64x32, row-major W[k*32+c]); built once, L2-hot.
    half8_t b00, b01, b10, b11;
    #pragma unroll
    for (int j = 0; j < 8; ++j) {
        b00[j] = (_Float16)W[(kb + j) * OUT_F + m];
        b01[j] = (_Float16)W[(32 + kb + j) * OUT_F + m];
        b10[j] = (_Float16)W[(kb + j) * OUT_F + 16 + m];
        b11[j] = (_Float16)W[(32 + kb + j) * OUT_F + 16 + m];
    }
    // A fragments: x row (clamped in the tail block), 2x float4 per K-chunk.
    const int row = min(node0 + m, N - 1);
    const float* xr = x + (size_t)row * IN_F + kb;
    float4_t xa = *(const float4_t*)(xr);
    float4_t xb = *(const float4_t*)(xr + 4);
    float4_t xc = *(const float4_t*)(xr + 32);
    float4_t xd = *(const float4_t*)(xr + 36);
    half8_t a0, a1;
    #pragma unroll
    for (int j = 0; j < 4; ++j) {
        a0[j] = (_Float16)xa[j]; a0[4 + j] = (_Float16)xb[j];
        a1[j] = (_Float16)xc[j]; a1[4 + j] = (_Float16)xd[j];
    }
    float4_t acc0 = {0.f, 0.f, 0.f, 0.f};
    float4_t acc1 = {0.f, 0.f, 0.f, 0.f};
    acc0 = __builtin_amdgcn_mfma_f32_16x16x32_f16(a0, b00, acc0, 0, 0, 0);
    acc0 = __builtin_amdgcn_mfma_f32_16x16x32_f16(a1, b01, acc0, 0, 0, 0);
    acc1 = __builtin_amdgcn_mfma_f32_16x16x32_f16(a0, b10, acc1, 0, 0, 0);
    acc1 = __builtin_amdgcn_mfma_f32_16x16x32_f16(a1, b11, acc1, 0, 0, 0);

    // Epilogue: h2 (fp16 pairs) + asrc/adst per node.
    const float aS0 = att_src[m], aS1 = att_src[16 + m];
    const float aD0 = att_dst[m], aD1 = att_dst[16 + m];
    #pragma unroll
    for (int r = 0; r < 4; ++r) {
        const int node = node0 + quad * 4 + r;
        float h0 = acc0[r], h1 = acc1[r];
        float h0p = __shfl_xor(h0, 1);
        float h1p = __shfl_xor(h1, 1);
        if (node < N && (m & 1) == 0) {
            __half2 hv;
            hv.x = __float2half_rn(h0); hv.y = __float2half_rn(h0p);
            h2[(size_t)node * 16 + (m >> 1)] = hv;
            __half2 hw;
            hw.x = __float2half_rn(h1); hw.y = __float2half_rn(h1p);
            h2[(size_t)node * 16 + 8 + (m >> 1)] = hw;
        }
        float vs = h0 * aS0 + h1 * aS1;
        float vd = h0 * aD0 + h1 * aD1;
        #pragma unroll
        for (int mm = 1; mm < 16; mm <<= 1) {
            vs += __shfl_xor(vs, mm);
            vd += __shfl_xor(vd, mm);
        }
        if (node < N && m == 0) {
            asrc[node] = vs;
            adst[node] = vd;
        }
    }
}

// Scan 1: one block per bucket; exclusive scan of hist[b][0..NBLKA) in place,
// bucket total -> bsum[b].
__global__ __launch_bounds__(256) void k_scan1(int* __restrict__ hist,
                                               int* __restrict__ bsum, int NB) {
    __shared__ int wsum[4];
    const int b = blockIdx.x, tid = threadIdx.x;
    int v = hist[(size_t)b * NBLKA + tid];
    const int inc = incScan256(v, tid, wsum);
    hist[(size_t)b * NBLKA + tid] = inc - v;
    if (tid == 255) bsum[b] = inc;
}

// Pass B: 512 threads/block. Locally scan bucket totals -> bbase (LDS), seed
// per-bucket cursors, place packed records (d&127)<<17 | s into private runs.
// Block 0 additionally publishes the bucket-offset scan to boff[0..NB].
__global__ __launch_bounds__(512) void k_bpart(const int* __restrict__ src,
                                               const int* __restrict__ dst,
                                               const int* __restrict__ hist,
                                               const int* __restrict__ bsum,
                                               int* __restrict__ recs,
                                               int* __restrict__ boff,
                                               int NB, int E, int epb) {
    __shared__ int tt[NBMAX];
    __shared__ int lcur[NBMAX];
    __shared__ int wsum[8];
    const int tid = threadIdx.x, blk = blockIdx.x;
    for (int i = tid; i < NBMAX; i += 512) tt[i] = (i < NB) ? bsum[i] : 0;
    __syncthreads();
    {
        int a0 = tt[tid * 2], a1 = tt[tid * 2 + 1];
        int s = a0 + a1;
        int inc = incScan512(s, tid, wsum);
        int run = inc - s;
        tt[tid * 2] = run; run += a0;
        tt[tid * 2 + 1] = run;
    }
    __syncthreads();
    if (blk == 0) {
        for (int b = tid; b < NB; b += 512) boff[b] = tt[b];
        if (tid == 0) boff[NB] = E;
    }
    for (int b = tid; b < NB; b += 512)
        lcur[b] = hist[(size_t)b * NBLKA + blk] + tt[b];
    __syncthreads();
    const int e0 = blk * epb, e1 = min(E, e0 + epb);
    for (int e = e0 + tid; e < e1; e += 512) {
        int s = src[e];
        int d = dst[e];
        int p = atomicAdd(&lcur[d >> BK_SHIFT], 1);   // LDS cursor, block-private
        recs[p] = ((d & (BK - 1)) << 17) | s;
    }
}

// Aggregate: one block per bucket (128 nodes, 512 threads). No fine sort —
// each thread consumes packed records directly, computes the un-normalized
// attention weight p once per edge, and accumulates p and p*h into LDS
// acc[128][33] (channel 32 = denominator; stride 33 -> bank (d+c)%32, so
// random-d lanes spread across banks). Finalize adds the self loop, divides,
// adds bias, relu, and writes the output row.
__global__ __launch_bounds__(512) void k_agg(const int* __restrict__ recs,
                                             const int* __restrict__ boff,
                                             const float* __restrict__ asrc,
                                             const float* __restrict__ adst,
                                             const __half2* __restrict__ h2,
                                             const float* __restrict__ bias,
                                             float* __restrict__ out,
                                             int NB, int E, int N) {
    __shared__ float acc[BK * 33];     // 16896 B
    __shared__ float adl[BK];
    const int b = blockIdx.x, tid = threadIdx.x;
    const int node0 = b << BK_SHIFT;

    for (int i = tid; i < BK * 33; i += 512) acc[i] = 0.0f;
    if (tid < BK) {
        const int n = node0 + tid;
        adl[tid] = (n < N) ? adst[n] : 0.0f;
    }
    __syncthreads();

    const int cb0 = boff[b];
    const int cb1 = boff[b + 1];

    int i = cb0 + tid;
    int r = (i < cb1) ? recs[i] : 0;
    while (i < cb1) {
        const int inext = i + 512;
        const int rn = (inext < cb1) ? recs[inext] : 0;   // prefetch
        const int s = r & 0x1FFFF;
        const int d = r >> 17;
        // h2 row: 64 B as 4x dwordx4
        const int4_t* hp = (const int4_t*)(h2 + (size_t)s * 16);
        const int4_t q0 = hp[0], q1 = hp[1], q2 = hp[2], q3 = hp[3];
        const float p = __expf(leaky(asrc[s] + adl[d]));
        float* accd = acc + d * 33;
        unsafeAtomicAdd(accd + 32, p);
        #pragma unroll
        for (int k = 0; k < 4; ++k) {
            const int4_t q = (k == 0) ? q0 : (k == 1) ? q1 : (k == 2) ? q2 : q3;
            #pragma unroll
            for (int j = 0; j < 4; ++j) {
                const float2 f = h2f(q[j]);
                unsafeAtomicAdd(accd + (k * 4 + j) * 2,     p * f.x);
                unsafeAtomicAdd(accd + (k * 4 + j) * 2 + 1, p * f.y);
            }
        }
        i = inext; r = rn;
    }
    __syncthreads();

    // Finalize: 4 threads per node, 8 channels each.
    const int d  = tid >> 2;            // 0..127
    const int cb = (tid & 3) * 8;       // channel base
    const int n  = node0 + d;
    if (n < N) {
        const float ps = __expf(leaky(asrc[n] + adl[d]));   // self loop
        const float* accd = acc + d * 33;
        const float inv = 1.0f / (accd[32] + ps);
        // self h for channels cb..cb+7: 4 half2 = 16 B
        const int4_t hq = *(const int4_t*)(h2 + (size_t)n * 16 + (cb >> 1));
        float4_t o0, o1;
        #pragma unroll
        for (int k = 0; k < 4; ++k) {
            const float2 f = h2f(hq[k]);
            const float v0 = (accd[cb + 2 * k]     + ps * f.x) * inv + bias[cb + 2 * k];
            const float v1 = (accd[cb + 2 * k + 1] + ps * f.y) * inv + bias[cb + 2 * k + 1];
            if (k < 2) { o0[2 * k] = fmaxf(v0, 0.0f); o0[2 * k + 1] = fmaxf(v1, 0.0f); }
            else       { o1[2 * (k - 2)] = fmaxf(v0, 0.0f); o1[2 * (k - 2) + 1] = fmaxf(v1, 0.0f); }
        }
        float4_t* op = (float4_t*)(out + (size_t)n * OUT_F + cb);
        op[0] = o0;
        op[1] = o1;
    }
}

extern "C" void kernel_launch(void* const* d_in, const int* in_sizes, int n_in,
                              void* d_out, int out_size, void* d_ws, size_t ws_size,
                              hipStream_t stream) {
    const float* x        = (const float*)d_in[0];
    const int*   eidx     = (const int*)d_in[1];   // [2, E] flat int32
    const float* W        = (const float*)d_in[2];
    const float* att_src  = (const float*)d_in[3];
    const float* att_dst  = (const float*)d_in[4];
    const float* bias     = (const float*)d_in[5];
    float* out = (float*)d_out;

    const int N = in_sizes[0] / IN_F;
    const int E = in_sizes[1] / 2;
    const int* src = eidx;
    const int* dst = eidx + E;

    const int NB  = (N + BK - 1) >> BK_SHIFT;    // 782 buckets
    const int epb = (E + NBLKA - 1) / NBLKA;     // edges per hist/bpart block

    // Workspace (4 B elems, ~14.6 MB)
    int* u = (int*)d_ws;
    size_t o = 0;
    __half2* h2   = (__half2*)(u + o); o += (size_t)N * 16;   // N*16 half2
    float*   asrc = (float*)(u + o);   o += N;
    float*   adst = (float*)(u + o);   o += N;
    int*     hist = u + o;             o += (size_t)NB * NBLKA;  // ~200k
    int*     bsum = u + o;             o += NBMAX;
    int*     boff = u + o;             o += NBMAX + 1;
    int*     recs = u + o;             o += E;

    const int PB = (N + 63) / 64;                // MFMA proj blocks (64 nodes/block)

    k_projhist<<<PB + NBLKA, 256, 0, stream>>>(x, W, att_src, att_dst, h2, asrc, adst,
                                               dst, hist, N, NB, E, epb, PB);
    k_scan1<<<NB, 256, 0, stream>>>(hist, bsum, NB);
    k_bpart<<<NBLKA, 512, 0, stream>>>(src, dst, hist, bsum, recs, boff, NB, E, epb);
    k_agg<<<NB, 512, 0, stream>>>(recs, boff, asrc, adst, h2, bias, out, NB, E, N);
}

// Round 3
// 463.083 us; speedup vs baseline: 1.0057x; 1.0057x over previous
//
#include <hip/hip_runtime.h>
#include <hip/hip_fp16.h>
#include <math.h>

#define IN_F 64
#define OUT_F 32
#define NEG_SLOPE 0.2f

#define BK_SHIFT 7
#define BK 128           // nodes per bucket
#define NBMAX 1024       // max buckets (N <= 131072)
#define NBLKA 256        // edge-pass block count (= per-bucket scan width)

typedef _Float16 half8_t __attribute__((ext_vector_type(8)));
typedef float float4_t __attribute__((ext_vector_type(4)));
typedef int int4_t __attribute__((ext_vector_type(4)));

__device__ __forceinline__ float leaky(float v) {
    return (v > 0.0f) ? v : NEG_SLOPE * v;
}

__device__ __forceinline__ float2 h2f(int w) {
    __half2 h = *reinterpret_cast<__half2*>(&w);
    return __half22float2(h);
}

// Inclusive block scan, 256 threads. wsum: >=4-int LDS scratch.
__device__ __forceinline__ int incScan256(int v, int tid, int* wsum) {
    const int lane = tid & 63, wid = tid >> 6;
    #pragma unroll
    for (int m = 1; m < 64; m <<= 1) {
        int u = __shfl_up(v, m);
        if (lane >= m) v += u;
    }
    if (lane == 63) wsum[wid] = v;
    __syncthreads();
    int add = 0;
    for (int k = 0; k < wid; ++k) add += wsum[k];
    __syncthreads();
    return v + add;
}

// Inclusive block scan, 512 threads. wsum: >=8-int LDS scratch.
__device__ __forceinline__ int incScan512(int v, int tid, int* wsum) {
    const int lane = tid & 63, wid = tid >> 6;
    #pragma unroll
    for (int m = 1; m < 64; m <<= 1) {
        int u = __shfl_up(v, m);
        if (lane >= m) v += u;
    }
    if (lane == 63) wsum[wid] = v;
    __syncthreads();
    int add = 0;
    for (int k = 0; k < wid; ++k) add += wsum[k];
    __syncthreads();
    return v + add;
}

// Fused: blocks [0, PB) MFMA projection (16 nodes/wave, 64/block, no LDS);
// blocks [PB, PB+NBLKA) coarse histogram (LDS).
// MFMA layouts (HW-verified, cdna_hip_programming.md §3 / m89/m120):
//   A[m=lane&15][k=(lane>>4)*8+j]   B[n=lane&15][k=(lane>>4)*8+j]
//   C/D: col(n)=lane&15, row(m)=(lane>>4)*4+reg
__global__ __launch_bounds__(256) void k_projhist(
        const float* __restrict__ x, const float* __restrict__ W,
        const float* __restrict__ att_src, const float* __restrict__ att_dst,
        __half2* __restrict__ h2, float* __restrict__ asrc, float* __restrict__ adst,
        const int* __restrict__ dst, int* __restrict__ hist,
        int N, int NB, int E, int epb, int PB) {
    __shared__ int smem[2560];               // 10 KB (hist role only)
    const int tid = threadIdx.x;

    if (blockIdx.x >= PB) {
        // ---- coarse histogram role: hist[b*NBLKA + blk] ----
        int* lh = smem;
        const int blk = blockIdx.x - PB;
        for (int i = tid; i < NB; i += 256) lh[i] = 0;
        __syncthreads();
        const int e0 = blk * epb, e1 = min(E, e0 + epb);
        for (int e = e0 + tid; e < e1; e += 256) atomicAdd(&lh[dst[e] >> BK_SHIFT], 1);
        __syncthreads();
        for (int b = tid; b < NB; b += 256) hist[(size_t)b * NBLKA + blk] = lh[b];
        return;
    }

    // ---- MFMA projection role ----
    const int wv   = tid >> 6;               // wave 0..3
    const int lane = tid & 63;
    const int m    = lane & 15;              // node-in-16 (A) / channel-in-group (B, C/D)
    const int quad = lane >> 4;              // 0..3
    const int node0 = (blockIdx.x * 4 + wv) * 16;
    if (node0 >= N) return;

    const int kb = quad * 8;
    // B fragments (W is 64x32, row-major W[k*32+c]); built once, L2-hot.
    half8_t b00, b01, b10, b11;
    #pragma unroll
    for (int j = 0; j < 8; ++j) {
        b00[j] = (_Float16)W[(kb + j) * OUT_F + m];
        b01[j] = (_Float16)W[(32 + kb + j) * OUT_F + m];
        b10[j] = (_Float16)W[(kb + j) * OUT_F + 16 + m];
        b11[j] = (_Float16)W[(32 + kb + j) * OUT_F + 16 + m];
    }
    // A fragments: x row (clamped in the tail block), 2x float4 per K-chunk.
    const int row = min(node0 + m, N - 1);
    const float* xr = x + (size_t)row * IN_F + kb;
    float4_t xa = *(const float4_t*)(xr);
    float4_t xb = *(const float4_t*)(xr + 4);
    float4_t xc = *(const float4_t*)(xr + 32);
    float4_t xd = *(const float4_t*)(xr + 36);
    half8_t a0, a1;
    #pragma unroll
    for (int j = 0; j < 4; ++j) {
        a0[j] = (_Float16)xa[j]; a0[4 + j] = (_Float16)xb[j];
        a1[j] = (_Float16)xc[j]; a1[4 + j] = (_Float16)xd[j];
    }
    float4_t acc0 = {0.f, 0.f, 0.f, 0.f};
    float4_t acc1 = {0.f, 0.f, 0.f, 0.f};
    acc0 = __builtin_amdgcn_mfma_f32_16x16x32_f16(a0, b00, acc0, 0, 0, 0);
    acc0 = __builtin_amdgcn_mfma_f32_16x16x32_f16(a1, b01, acc0, 0, 0, 0);
    acc1 = __builtin_amdgcn_mfma_f32_16x16x32_f16(a0, b10, acc1, 0, 0, 0);
    acc1 = __builtin_amdgcn_mfma_f32_16x16x32_f16(a1, b11, acc1, 0, 0, 0);

    // Epilogue: h2 (fp16 pairs) + asrc/adst per node.
    const float aS0 = att_src[m], aS1 = att_src[16 + m];
    const float aD0 = att_dst[m], aD1 = att_dst[16 + m];
    #pragma unroll
    for (int r = 0; r < 4; ++r) {
        const int node = node0 + quad * 4 + r;
        float h0 = acc0[r], h1 = acc1[r];
        float h0p = __shfl_xor(h0, 1);
        float h1p = __shfl_xor(h1, 1);
        if (node < N && (m & 1) == 0) {
            __half2 hv;
            hv.x = __float2half_rn(h0); hv.y = __float2half_rn(h0p);
            h2[(size_t)node * 16 + (m >> 1)] = hv;
            __half2 hw;
            hw.x = __float2half_rn(h1); hw.y = __float2half_rn(h1p);
            h2[(size_t)node * 16 + 8 + (m >> 1)] = hw;
        }
        float vs = h0 * aS0 + h1 * aS1;
        float vd = h0 * aD0 + h1 * aD1;
        #pragma unroll
        for (int mm = 1; mm < 16; mm <<= 1) {
            vs += __shfl_xor(vs, mm);
            vd += __shfl_xor(vd, mm);
        }
        if (node < N && m == 0) {
            asrc[node] = vs;
            adst[node] = vd;
        }
    }
}

// Scan 1: one block per bucket; exclusive scan of hist[b][0..NBLKA) in place,
// bucket total -> bsum[b].
__global__ __launch_bounds__(256) void k_scan1(int* __restrict__ hist,
                                               int* __restrict__ bsum, int NB) {
    __shared__ int wsum[4];
    const int b = blockIdx.x, tid = threadIdx.x;
    int v = hist[(size_t)b * NBLKA + tid];
    const int inc = incScan256(v, tid, wsum);
    hist[(size_t)b * NBLKA + tid] = inc - v;
    if (tid == 255) bsum[b] = inc;
}

// Pass B: 512 threads/block. Locally scan bucket totals -> bbase (LDS), seed
// per-bucket cursors, place packed records (d&127)<<17 | s into private runs.
// Block 0 additionally publishes the bucket-offset scan to boff[0..NB].
__global__ __launch_bounds__(512) void k_bpart(const int* __restrict__ src,
                                               const int* __restrict__ dst,
                                               const int* __restrict__ hist,
                                               const int* __restrict__ bsum,
                                               int* __restrict__ recs,
                                               int* __restrict__ boff,
                                               int NB, int E, int epb) {
    __shared__ int tt[NBMAX];
    __shared__ int lcur[NBMAX];
    __shared__ int wsum[8];
    const int tid = threadIdx.x, blk = blockIdx.x;
    for (int i = tid; i < NBMAX; i += 512) tt[i] = (i < NB) ? bsum[i] : 0;
    __syncthreads();
    {
        int a0 = tt[tid * 2], a1 = tt[tid * 2 + 1];
        int s = a0 + a1;
        int inc = incScan512(s, tid, wsum);
        int run = inc - s;
        tt[tid * 2] = run; run += a0;
        tt[tid * 2 + 1] = run;
    }
    __syncthreads();
    if (blk == 0) {
        for (int b = tid; b < NB; b += 512) boff[b] = tt[b];
        if (tid == 0) boff[NB] = E;
    }
    for (int b = tid; b < NB; b += 512)
        lcur[b] = hist[(size_t)b * NBLKA + blk] + tt[b];
    __syncthreads();
    const int e0 = blk * epb, e1 = min(E, e0 + epb);
    for (int e = e0 + tid; e < e1; e += 512) {
        int s = src[e];
        int d = dst[e];
        int p = atomicAdd(&lcur[d >> BK_SHIFT], 1);   // LDS cursor, block-private
        recs[p] = ((d & (BK - 1)) << 17) | s;
    }
}

// Aggregate: one block per bucket (128 nodes, 512 threads). No fine sort —
// each thread consumes packed records directly, computes the un-normalized
// attention weight p once per edge, and accumulates p and p*h into LDS
// acc[128][33] (channel 32 = denominator; stride 33 -> bank (d+c)%32, so
// random-d lanes spread across banks). All accumulation via plain atomicAdd
// on the __shared__ array -> hardware ds_add_f32 (NOT unsafeAtomicAdd, which
// lowered to a flat/global atomic into the LDS aperture: 355us, VALUBusy 1.2%).
// Finalize adds the self loop, divides, adds bias, relu, writes output row.
__global__ __launch_bounds__(512) void k_agg(const int* __restrict__ recs,
                                             const int* __restrict__ boff,
                                             const float* __restrict__ asrc,
                                             const float* __restrict__ adst,
                                             const __half2* __restrict__ h2,
                                             const float* __restrict__ bias,
                                             float* __restrict__ out,
                                             int NB, int E, int N) {
    __shared__ float acc[BK * 33];     // 16896 B
    __shared__ float adl[BK];
    const int b = blockIdx.x, tid = threadIdx.x;
    const int node0 = b << BK_SHIFT;

    for (int i = tid; i < BK * 33; i += 512) acc[i] = 0.0f;
    if (tid < BK) {
        const int n = node0 + tid;
        adl[tid] = (n < N) ? adst[n] : 0.0f;
    }
    __syncthreads();

    const int cb0 = boff[b];
    const int cb1 = boff[b + 1];

    int i = cb0 + tid;
    int r = (i < cb1) ? recs[i] : 0;
    while (i < cb1) {
        const int inext = i + 512;
        const int rn = (inext < cb1) ? recs[inext] : 0;   // prefetch
        const int s = r & 0x1FFFF;
        const int d = r >> 17;
        // h2 row: 64 B as 4x dwordx4
        const int4_t* hp = (const int4_t*)(h2 + (size_t)s * 16);
        const int4_t q0 = hp[0], q1 = hp[1], q2 = hp[2], q3 = hp[3];
        const float p = __expf(leaky(asrc[s] + adl[d]));
        const int dbase = d * 33;
        atomicAdd(&acc[dbase + 32], p);
        #pragma unroll
        for (int k = 0; k < 4; ++k) {
            const int4_t q = (k == 0) ? q0 : (k == 1) ? q1 : (k == 2) ? q2 : q3;
            #pragma unroll
            for (int j = 0; j < 4; ++j) {
                const float2 f = h2f(q[j]);
                atomicAdd(&acc[dbase + (k * 4 + j) * 2],     p * f.x);
                atomicAdd(&acc[dbase + (k * 4 + j) * 2 + 1], p * f.y);
            }
        }
        i = inext; r = rn;
    }
    __syncthreads();

    // Finalize: 4 threads per node, 8 channels each.
    const int d  = tid >> 2;            // 0..127
    const int cb = (tid & 3) * 8;       // channel base
    const int n  = node0 + d;
    if (n < N) {
        const float ps = __expf(leaky(asrc[n] + adl[d]));   // self loop
        const float* accd = acc + d * 33;
        const float inv = 1.0f / (accd[32] + ps);
        // self h for channels cb..cb+7: 4 half2 = 16 B
        const int4_t hq = *(const int4_t*)(h2 + (size_t)n * 16 + (cb >> 1));
        float4_t o0, o1;
        #pragma unroll
        for (int k = 0; k < 4; ++k) {
            const float2 f = h2f(hq[k]);
            const float v0 = (accd[cb + 2 * k]     + ps * f.x) * inv + bias[cb + 2 * k];
            const float v1 = (accd[cb + 2 * k + 1] + ps * f.y) * inv + bias[cb + 2 * k + 1];
            if (k < 2) { o0[2 * k] = fmaxf(v0, 0.0f); o0[2 * k + 1] = fmaxf(v1, 0.0f); }
            else       { o1[2 * (k - 2)] = fmaxf(v0, 0.0f); o1[2 * (k - 2) + 1] = fmaxf(v1, 0.0f); }
        }
        float4_t* op = (float4_t*)(out + (size_t)n * OUT_F + cb);
        op[0] = o0;
        op[1] = o1;
    }
}

extern "C" void kernel_launch(void* const* d_in, const int* in_sizes, int n_in,
                              void* d_out, int out_size, void* d_ws, size_t ws_size,
                              hipStream_t stream) {
    const float* x        = (const float*)d_in[0];
    const int*   eidx     = (const int*)d_in[1];   // [2, E] flat int32
    const float* W        = (const float*)d_in[2];
    const float* att_src  = (const float*)d_in[3];
    const float* att_dst  = (const float*)d_in[4];
    const float* bias     = (const float*)d_in[5];
    float* out = (float*)d_out;

    const int N = in_sizes[0] / IN_F;
    const int E = in_sizes[1] / 2;
    const int* src = eidx;
    const int* dst = eidx + E;

    const int NB  = (N + BK - 1) >> BK_SHIFT;    // 782 buckets
    const int epb = (E + NBLKA - 1) / NBLKA;     // edges per hist/bpart block

    // Workspace (4 B elems, ~14.6 MB)
    int* u = (int*)d_ws;
    size_t o = 0;
    __half2* h2   = (__half2*)(u + o); o += (size_t)N * 16;   // N*16 half2
    float*   asrc = (float*)(u + o);   o += N;
    float*   adst = (float*)(u + o);   o += N;
    int*     hist = u + o;             o += (size_t)NB * NBLKA;  // ~200k
    int*     bsum = u + o;             o += NBMAX;
    int*     boff = u + o;             o += NBMAX + 1;
    int*     recs = u + o;             o += E;

    const int PB = (N + 63) / 64;                // MFMA proj blocks (64 nodes/block)

    k_projhist<<<PB + NBLKA, 256, 0, stream>>>(x, W, att_src, att_dst, h2, asrc, adst,
                                               dst, hist, N, NB, E, epb, PB);
    k_scan1<<<NB, 256, 0, stream>>>(hist, bsum, NB);
    k_bpart<<<NBLKA, 512, 0, stream>>>(src, dst, hist, bsum, recs, boff, NB, E, epb);
    k_agg<<<NB, 512, 0, stream>>>(recs, boff, asrc, adst, h2, bias, out, NB, E, N);
}